// Round 16
// baseline (64.798 us; speedup 1.0000x reference)
//
#include <hip/hip_runtime.h>
#include <math.h>

#define LOG2E 1.4426950408889634f

typedef __attribute__((ext_vector_type(8))) short    short8;   // 8 bf16
typedef __attribute__((ext_vector_type(8))) _Float16 half8;    // 8 f16 (4 VGPR)
typedef __attribute__((ext_vector_type(4))) float    f32x4;    // MFMA C/D
typedef __attribute__((ext_vector_type(2))) float    f32x2;    // packed pair

__device__ __forceinline__ float fexp2(float x) { return __builtin_amdgcn_exp2f(x); }

// async global->LDS, 16B/lane: LDS dest = wave-uniform base + lane*16;
// per-lane global source; offset immediate ALWAYS 0 (R9/R10 lesson).
typedef __attribute__((address_space(1))) const unsigned int gas_u32;
typedef __attribute__((address_space(3))) unsigned int las_u32;
__device__ __forceinline__ void glds16(const uint4* g, uint4* l)
{ __builtin_amdgcn_global_load_lds((gas_u32*)g, (las_u32*)l, 16, 0, 0); }

// counted-vmcnt + raw barrier pair (T3/T4, m201-validated pattern).
#define WAIT_BARRIER(N)                                          \
    do {                                                         \
        asm volatile("s_waitcnt vmcnt(" #N ")" ::: "memory");    \
        __builtin_amdgcn_sched_barrier(0);                       \
        __builtin_amdgcn_s_barrier();                            \
        __builtin_amdgcn_sched_barrier(0);                       \
    } while (0)

// 21 Gaussian kernels for 2 sims -> acc[21] (f32x2), DEFERRED normalization
// (validated R6-R13): g_{9+j}(s) = gc * v^j * e^{-j^2/2}, v = e^{10s+0.5},
// gc = e^{-50(s+0.05)^2}; c_j applied at the fold. Exact kernel (mu=1,
// sigma=0.001) via guarded FP path (wave-uniform skip, ~0.1% taken).
__device__ __forceinline__ void kern21(f32x2 s, f32x2* acc)
{
    s.x = __builtin_amdgcn_fmed3f(s.x, -1.1f, 1.1f);
    s.y = __builtin_amdgcn_fmed3f(s.y, -1.1f, 1.1f);

    f32x2 va = s * 14.426950408889634f + 0.7213475204444817f;  // log2(e)*(10s+0.5)
    f32x2 v, vi, gc;
    v.x  = fexp2(va.x);  v.y  = fexp2(va.y);
    vi.x = __builtin_amdgcn_rcpf(v.x);
    vi.y = __builtin_amdgcn_rcpf(v.y);
    f32x2 t9 = s + 0.05f;
    f32x2 ga = (t9 * t9) * -72.13475204444817f;                // -50/ln2
    gc.x = fexp2(ga.x);  gc.y = fexp2(ga.y);

    f32x2 p = gc;
    acc[9] += p;
    #pragma unroll
    for (int k = 10; k <= 19; ++k) { p *= v; acc[k] += p; }    // up: j=1..10
    f32x2 q = gc;
    #pragma unroll
    for (int k = 8; k >= 0; --k) { q *= vi; acc[k] += q; }     // down: j=1..9
    if (__any(fmaxf(s.x, s.y) > 0.995f)) {
        f32x2 te = s - 1.0f;
        f32x2 ea = (te * te) * -721347.5204444817f;
        f32x2 ge; ge.x = fexp2(ea.x); ge.y = fexp2(ea.y);
        acc[20] += ge;
    }
}

// One 16x16 sim tile, f16 single-precision: 2 MFMAs + 2x kern21.
// (f16 accuracy validated end-to-end in R12/R13.)
__device__ __forceinline__ void doc_step2(
    half8 A0, half8 A1, half8 B0, half8 B1, f32x2* acc)
{
    f32x4 C = {0.f, 0.f, 0.f, 0.f};
    C = __builtin_amdgcn_mfma_f32_16x16x32_f16(A0, B0, C, 0, 0, 0);
    C = __builtin_amdgcn_mfma_f32_16x16x32_f16(A1, B1, C, 0, 0, 0);
    f32x2 a01 = {C[0], C[1]};
    f32x2 a23 = {C[2], C[3]};
    kern21(a01, acc);
    kern21(a23, acc);
}

// ---- prep: normalize (f32) + convert to f16; 64 f16 = 128 B per token ----
// layout: wse[tok*8 + c] = chunk c (8 f16), elements 50..63 zero.
__global__ __launch_bounds__(256) void knrm_prep_kernel(
    const float* __restrict__ emb, uint4* __restrict__ wse, int vocab)
{
    const int tid = threadIdx.x;
    const int row = blockIdx.x * 32 + (tid >> 3);
    const int cb  = tid & 7;
    if (row >= vocab) return;   // whole 8-lane group exits together

    const float* src = emb + (size_t)row * 50;
    float v[8];
    float ss = 0.f;
    #pragma unroll
    for (int p = 0; p < 4; ++p) {
        int e = cb * 8 + 2 * p;
        float2 t;
        if (e + 2 <= 50) t = *(const float2*)(src + e);
        else             t = make_float2(0.f, 0.f);
        v[2*p]   = t.x;
        v[2*p+1] = t.y;
        ss = fmaf(t.x, t.x, fmaf(t.y, t.y, ss));
    }
    ss += __shfl_xor(ss, 1, 64);
    ss += __shfl_xor(ss, 2, 64);
    ss += __shfl_xor(ss, 4, 64);
    float rn = __builtin_amdgcn_rsqf(ss);

    half8 hv;
    #pragma unroll
    for (int p = 0; p < 8; ++p) hv[p] = (_Float16)(v[p] * rn);
    wse[(size_t)row * 8 + cb] = __builtin_bit_cast(uint4, hv);
}

__device__ __forceinline__ half8 frag_ldh(const uint4* mat, int row, int chunk)
{
    return __builtin_bit_cast(half8, mat[row * 8 + (chunk ^ (row & 7))]);
}

// ==== main pass kernel (PRE): R13 structure + T3/T4 counted-vmcnt pipeline ====
// Triple-buffered 64-row chunks; per chunk: issue glds(c+2) -> compute(c) ->
// s_waitcnt vmcnt(2) [chunk c+1 landed; c+2 stays IN FLIGHT across the
// barrier] -> raw s_barrier. The compiler's vmcnt(0)-drain before
// __syncthreads was the R13 stall (R15: occupancy knob flat -> drain is the
// residual). didx staged to LDS so token reads are lgkm (vmcnt ledger clean:
// exactly 2 glds/wave/chunk). vmcnt ledger traced over all 8 iters.
__global__ __launch_bounds__(256, 5) void knrm_pass_pre(
    const int* __restrict__ q1, const int* __restrict__ d1,
    const int* __restrict__ q2, const int* __restrict__ d2,
    const uint4* __restrict__ wse, const float* __restrict__ mlp_w,
    float* __restrict__ ws_logit)
{
    __shared__ uint4 dbuf[3][512];      // 24 KB (Q overlays dbuf[2] in prologue)
    __shared__ int   didxL[512];        // 2 KB
    __shared__ float Swk[4][21][16];
    __shared__ float wred[4];

    const int tid  = threadIdx.x;
    const int bx   = blockIdx.x;        // b*2 + pass
    const int b    = bx >> 1;
    const int lane = tid & 63;
    const int wave = tid >> 6;
    const int g    = lane >> 4;         // k-group 0..3

    const int* qidx = ((bx & 1) ? q2 : q1) + b * 32;
    const int* didx = ((bx & 1) ? d2 : d1) + b * 512;

    const int rsub = lane >> 3;         // staging sub-row 0..7
    const int cpos = lane & 7;          // linear chunk pos in row
    const int swz  = cpos ^ rsub;       // global chunk to fetch for this pos

    // ---- prologue ----
    didxL[tid]       = didx[tid];
    didxL[256 + tid] = didx[256 + tid];
    {   // Q -> dbuf[2][0..256) (manual swizzled write)
        const int srow = tid >> 3, scb = tid & 7;
        const uint4* sq = wse + (size_t)qidx[srow] * 8;
        int pos = srow * 8 + (scb ^ (srow & 7));
        dbuf[2][pos] = sq[scb];
    }
    {   // doc chunks 0,1 -> dbuf[0],dbuf[1] via glds (wave w: rows 16w..16w+16)
        const uint4* p0 = wse + (size_t)didx[wave * 16 + rsub] * 8;
        const uint4* p1 = wse + (size_t)didx[wave * 16 + 8 + rsub] * 8;
        glds16(p0 + swz, &dbuf[0][wave * 128]);
        glds16(p1 + swz, &dbuf[0][wave * 128 + 64]);
        const uint4* pa = wse + (size_t)didx[64 + wave * 16 + rsub] * 8;
        const uint4* pb = wse + (size_t)didx[64 + wave * 16 + 8 + rsub] * 8;
        glds16(pa + swz, &dbuf[1][wave * 128]);
        glds16(pb + swz, &dbuf[1][wave * 128 + 64]);
    }
    __syncthreads();   // full drain: didxL + Q + chunks 0,1 ready; vmcnt = 0

    // ---- B fragments (registers, fixed all pass) from Q region ----
    const int qrow = (wave >> 1) * 16 + (lane & 15);
    half8 B0 = frag_ldh(dbuf[2], qrow, g);
    half8 B1 = frag_ldh(dbuf[2], qrow, 4 + g);
    __syncthreads();   // B reads done; dbuf[2] free for chunk 2

    // tokens for chunk 2 (issued at iter 0), read from LDS (lgkm, not vmcnt)
    int tokA = didxL[128 + wave * 16 + rsub];
    int tokB = didxL[128 + wave * 16 + 8 + rsub];

    f32x2 acc2[21];
    #pragma unroll
    for (int k = 0; k < 21; ++k) acc2[k] = (f32x2){0.f, 0.f};

    const int ar0 = (wave & 1) * 16 + (lane & 15);   // step-0 row in chunk
    const int ar1 = 32 + ar0;                        // step-1 row in chunk

    // ---- main pipeline: iters 0..5 issue chunk c+2; wait(2) retires c+1 ----
    #pragma unroll
    for (int c = 0; c < 6; ++c) {
        // 1) issue chunk c+2 into dbuf[(c+2)%3] (consumed by ALL waves at
        //    iter c-1's compute; iter c-1 ended with a barrier -> safe)
        {
            const uint4* pA = wse + (size_t)tokA * 8;
            const uint4* pB = wse + (size_t)tokB * 8;
            uint4* nb = dbuf[(c + 2) % 3];
            glds16(pA + swz, nb + wave * 128);
            glds16(pB + swz, nb + wave * 128 + 64);
        }
        if (c < 5) {   // tokens for chunk c+3 (used next iter)
            tokA = didxL[(c + 3) * 64 + wave * 16 + rsub];
            tokB = didxL[(c + 3) * 64 + wave * 16 + 8 + rsub];
        }
        // 2) compute chunk c (readiness guaranteed by previous wait+barrier)
        const uint4* hb = dbuf[c % 3];
        doc_step2(frag_ldh(hb, ar0, g), frag_ldh(hb, ar0, 4 + g), B0, B1, acc2);
        doc_step2(frag_ldh(hb, ar1, g), frag_ldh(hb, ar1, 4 + g), B0, B1, acc2);
        // 3) retire chunk c+1 (2 oldest); chunk c+2's 2 glds stay in flight
        WAIT_BARRIER(2);
    }
    // ---- tail: chunks 6,7 (no more issues) ----
    {
        const uint4* hb = dbuf[6 % 3];
        doc_step2(frag_ldh(hb, ar0, g), frag_ldh(hb, ar0, 4 + g), B0, B1, acc2);
        doc_step2(frag_ldh(hb, ar1, g), frag_ldh(hb, ar1, 4 + g), B0, B1, acc2);
        WAIT_BARRIER(0);   // chunk 7 landed (all waves)
    }
    {
        const uint4* hb = dbuf[7 % 3];
        doc_step2(frag_ldh(hb, ar0, g), frag_ldh(hb, ar0, 4 + g), B0, B1, acc2);
        doc_step2(frag_ldh(hb, ar1, g), frag_ldh(hb, ar1, 4 + g), B0, B1, acc2);
    }

    // ---- fold packed pair, then the 4 doc-row groups ----
    float acc[21];
    #pragma unroll
    for (int k = 0; k < 21; ++k) {
        float v = acc2[k].x + acc2[k].y;
        v += __shfl_xor(v, 16, 64);
        v += __shfl_xor(v, 32, 64);
        acc[k] = v;
    }
    if (lane < 16) {
        #pragma unroll
        for (int k = 0; k < 21; ++k) Swk[wave][k][lane] = acc[k];
    }
    __syncthreads();

    // ---- log1p + deferred c_j scale + kernel weights + block reduction ----
    float local = 0.f;
    for (int p = tid; p < 21 * 32; p += 256) {
        int k = p >> 5, q = p & 31;
        int wp = (q >> 4) * 2;     // waves {0,1}: q 0..15; {2,3}: q 16..31
        float S = Swk[wp][k][q & 15] + Swk[wp + 1][k][q & 15];
        float j = (float)(k - 9);
        float scale = (k < 20) ? fexp2(-0.7213475204444817f * j * j) : 1.0f;
        local += mlp_w[k] * log1pf(S * scale);
    }
    #pragma unroll
    for (int off = 1; off < 64; off <<= 1) local += __shfl_xor(local, off, 64);
    if (lane == 0) wred[wave] = local;
    __syncthreads();
    if (tid == 0)
        ws_logit[bx] = wred[0] + wred[1] + wred[2] + wred[3];  // bias cancels
}

// ==== fallback (ws too small): R2-proven bf16 hi/lo self-contained path ====
__device__ __forceinline__ short8 frag_ldb(const uint4* mat, int row, int chunk)
{
    return __builtin_bit_cast(short8, mat[row * 8 + (chunk ^ (row & 7))]);
}

__device__ __forceinline__ void doc_step_fb(
    short8 Ah0, short8 Ah1, short8 Al0, short8 Al1,
    short8 Bh0, short8 Bh1, short8 Bl0, short8 Bl1, f32x2* acc)
{
    f32x4 C = {0.f, 0.f, 0.f, 0.f};
    C = __builtin_amdgcn_mfma_f32_16x16x32_bf16(Ah0, Bh0, C, 0, 0, 0);
    C = __builtin_amdgcn_mfma_f32_16x16x32_bf16(Ah1, Bh1, C, 0, 0, 0);
    C = __builtin_amdgcn_mfma_f32_16x16x32_bf16(Ah0, Bl0, C, 0, 0, 0);
    C = __builtin_amdgcn_mfma_f32_16x16x32_bf16(Ah1, Bl1, C, 0, 0, 0);
    C = __builtin_amdgcn_mfma_f32_16x16x32_bf16(Al0, Bh0, C, 0, 0, 0);
    C = __builtin_amdgcn_mfma_f32_16x16x32_bf16(Al1, Bh1, C, 0, 0, 0);
    f32x2 a01 = {C[0], C[1]};
    f32x2 a23 = {C[2], C[3]};
    kern21(a01, acc);
    kern21(a23, acc);
}

__device__ __forceinline__ void stage_row_chunk(
    const float* __restrict__ emb, int tok, int row, int cb,
    uint4* __restrict__ hmat, uint4* __restrict__ lmat)
{
    const float* src = emb + (size_t)tok * 50;
    float v[8];
    float ss = 0.f;
    #pragma unroll
    for (int p = 0; p < 4; ++p) {
        int e = cb * 8 + 2 * p;
        float2 t;
        if (e + 2 <= 50) t = *(const float2*)(src + e);
        else             t = make_float2(0.f, 0.f);
        v[2*p]   = t.x;
        v[2*p+1] = t.y;
        ss = fmaf(t.x, t.x, fmaf(t.y, t.y, ss));
    }
    ss += __shfl_xor(ss, 1, 64);
    ss += __shfl_xor(ss, 2, 64);
    ss += __shfl_xor(ss, 4, 64);
    float rn = __builtin_amdgcn_rsqf(ss);

    unsigned hw[4], lw[4];
    #pragma unroll
    for (int p = 0; p < 4; ++p) {
        float a = v[2*p]   * rn;
        float b = v[2*p+1] * rn;
        unsigned ha = __float_as_uint(a) & 0xFFFF0000u;
        unsigned hb = __float_as_uint(b) & 0xFFFF0000u;
        float la = a - __uint_as_float(ha);
        float lb = b - __uint_as_float(hb);
        hw[p] = (ha >> 16) | hb;
        lw[p] = (__float_as_uint(la) >> 16) | (__float_as_uint(lb) & 0xFFFF0000u);
    }
    int cidx = cb ^ (row & 7);
    hmat[row * 8 + cidx] = make_uint4(hw[0], hw[1], hw[2], hw[3]);
    lmat[row * 8 + cidx] = make_uint4(lw[0], lw[1], lw[2], lw[3]);
}

__global__ __launch_bounds__(256, 4) void knrm_pass_fb(
    const int* __restrict__ q1, const int* __restrict__ d1,
    const int* __restrict__ q2, const int* __restrict__ d2,
    const float* __restrict__ emb, const float* __restrict__ mlp_w,
    float* __restrict__ ws_logit)
{
    __shared__ uint4 qh4[256], ql4[256];
    __shared__ uint4 dh4[256], dl4[256];
    __shared__ float Swk[4][21][16];
    __shared__ float wred[4];

    const int tid  = threadIdx.x;
    const int bx   = blockIdx.x;
    const int b    = bx >> 1;
    const int lane = tid & 63;
    const int wave = tid >> 6;
    const int g    = lane >> 4;

    const int* qidx = ((bx & 1) ? q2 : q1) + b * 32;
    const int* didx = ((bx & 1) ? d2 : d1) + b * 512;

    const int srow = tid >> 3;
    const int scb  = tid & 7;

    stage_row_chunk(emb, qidx[srow], srow, scb, qh4, ql4);
    __syncthreads();

    const int qrow = (wave >> 1) * 16 + (lane & 15);
    short8 Bh0 = frag_ldb(qh4, qrow, g);
    short8 Bh1 = frag_ldb(qh4, qrow, 4 + g);
    short8 Bl0 = frag_ldb(ql4, qrow, g);
    short8 Bl1 = frag_ldb(ql4, qrow, 4 + g);

    f32x2 acc2[21];
    #pragma unroll
    for (int k = 0; k < 21; ++k) acc2[k] = (f32x2){0.f, 0.f};

    const int arow = (wave & 1) * 16 + (lane & 15);

    for (int c = 0; c < 16; ++c) {
        if (c) __syncthreads();
        stage_row_chunk(emb, didx[c * 32 + srow], srow, scb, dh4, dl4);
        __syncthreads();
        doc_step_fb(frag_ldb(dh4, arow, g), frag_ldb(dh4, arow, 4 + g),
                    frag_ldb(dl4, arow, g), frag_ldb(dl4, arow, 4 + g),
                    Bh0, Bh1, Bl0, Bl1, acc2);
    }
    __syncthreads();

    float acc[21];
    #pragma unroll
    for (int k = 0; k < 21; ++k) {
        float v = acc2[k].x + acc2[k].y;
        v += __shfl_xor(v, 16, 64);
        v += __shfl_xor(v, 32, 64);
        acc[k] = v;
    }
    if (lane < 16) {
        #pragma unroll
        for (int k = 0; k < 21; ++k) Swk[wave][k][lane] = acc[k];
    }
    __syncthreads();

    float local = 0.f;
    for (int p = tid; p < 21 * 32; p += 256) {
        int k = p >> 5, q = p & 31;
        int wp = (q >> 4) * 2;
        float S = Swk[wp][k][q & 15] + Swk[wp + 1][k][q & 15];
        float j = (float)(k - 9);
        float scale = (k < 20) ? fexp2(-0.7213475204444817f * j * j) : 1.0f;
        local += mlp_w[k] * log1pf(S * scale);
    }
    #pragma unroll
    for (int off = 1; off < 64; off <<= 1) local += __shfl_xor(local, off, 64);
    if (lane == 0) wred[wave] = local;
    __syncthreads();
    if (tid == 0)
        ws_logit[bx] = wred[0] + wred[1] + wred[2] + wred[3];
}

__global__ void knrm_final_kernel(const float* __restrict__ P,
                                  float* __restrict__ out, int B)
{
    int i = blockIdx.x * 256 + threadIdx.x;
    if (i < B) {
        float x = P[2 * i] - P[2 * i + 1];
        out[i] = 1.0f / (1.0f + fexp2(-LOG2E * x));
    }
}

extern "C" void kernel_launch(void* const* d_in, const int* in_sizes, int n_in,
                              void* d_out, int out_size, void* d_ws, size_t ws_size,
                              hipStream_t stream) {
    const int*   q1    = (const int*)d_in[0];
    const int*   d1    = (const int*)d_in[1];
    const int*   q2    = (const int*)d_in[2];
    const int*   d2    = (const int*)d_in[3];
    const float* emb   = (const float*)d_in[4];
    const float* mlp_w = (const float*)d_in[5];
    float*       out   = (float*)d_out;

    const int B     = out_size;            // 1024
    const int vocab = in_sizes[4] / 50;    // 100000

    float* ws_logit = (float*)d_ws;                       // 2*B floats = 8192 B
    uint4* wse      = (uint4*)((char*)d_ws + 8192);       // f16 embeddings
    size_t need     = 8192 + (size_t)vocab * 128;

    if (ws_size >= need) {
        knrm_prep_kernel<<<dim3((vocab + 31) / 32), dim3(256), 0, stream>>>(emb, wse, vocab);
        knrm_pass_pre<<<dim3(2 * B), dim3(256), 0, stream>>>(
            q1, d1, q2, d2, wse, mlp_w, ws_logit);
    } else {
        knrm_pass_fb<<<dim3(2 * B), dim3(256), 0, stream>>>(
            q1, d1, q2, d2, emb, mlp_w, ws_logit);
    }
    knrm_final_kernel<<<dim3((B + 255) / 256), dim3(256), 0, stream>>>(ws_logit, out, B);
}

// Round 17
// 61.380 us; speedup vs baseline: 1.0557x; 1.0557x over previous
//
#include <hip/hip_runtime.h>
#include <math.h>

#define LOG2E 1.4426950408889634f

typedef __attribute__((ext_vector_type(8))) short    short8;   // 8 bf16
typedef __attribute__((ext_vector_type(8))) _Float16 half8;    // 8 f16 (4 VGPR)
typedef __attribute__((ext_vector_type(4))) float    f32x4;    // MFMA C/D
typedef __attribute__((ext_vector_type(2))) float    f32x2;    // packed pair

__device__ __forceinline__ float fexp2(float x) { return __builtin_amdgcn_exp2f(x); }

// async global->LDS, 16B/lane: LDS dest = wave-uniform base + lane*16;
// per-lane global source; offset immediate ALWAYS 0 (R9/R10 lesson).
typedef __attribute__((address_space(1))) const unsigned int gas_u32;
typedef __attribute__((address_space(3))) unsigned int las_u32;
__device__ __forceinline__ void glds16(const uint4* g, uint4* l)
{ __builtin_amdgcn_global_load_lds((gas_u32*)g, (las_u32*)l, 16, 0, 0); }

// 21 Gaussian kernels for 2 sims -> acc[21] (f32x2), DEFERRED normalization
// (validated R6-R15): g_{9+j}(s) = gc * v^j * e^{-j^2/2}, v = e^{10s+0.5},
// gc = e^{-50(s+0.05)^2}; c_j applied at the fold. Exact kernel (mu=1,
// sigma=0.001) via guarded FP path (wave-uniform skip, ~0.1% taken).
__device__ __forceinline__ void kern21(f32x2 s, f32x2* acc)
{
    s.x = __builtin_amdgcn_fmed3f(s.x, -1.1f, 1.1f);
    s.y = __builtin_amdgcn_fmed3f(s.y, -1.1f, 1.1f);

    f32x2 va = s * 14.426950408889634f + 0.7213475204444817f;  // log2(e)*(10s+0.5)
    f32x2 v, vi, gc;
    v.x  = fexp2(va.x);  v.y  = fexp2(va.y);
    vi.x = __builtin_amdgcn_rcpf(v.x);
    vi.y = __builtin_amdgcn_rcpf(v.y);
    f32x2 t9 = s + 0.05f;
    f32x2 ga = (t9 * t9) * -72.13475204444817f;                // -50/ln2
    gc.x = fexp2(ga.x);  gc.y = fexp2(ga.y);

    f32x2 p = gc;
    acc[9] += p;
    #pragma unroll
    for (int k = 10; k <= 19; ++k) { p *= v; acc[k] += p; }    // up: j=1..10
    f32x2 q = gc;
    #pragma unroll
    for (int k = 8; k >= 0; --k) { q *= vi; acc[k] += q; }     // down: j=1..9
    if (__any(fmaxf(s.x, s.y) > 0.995f)) {
        f32x2 te = s - 1.0f;
        f32x2 ea = (te * te) * -721347.5204444817f;
        f32x2 ge; ge.x = fexp2(ea.x); ge.y = fexp2(ea.y);
        acc[20] += ge;
    }
}

// One 16x16 sim tile, f16 single-precision: 2 MFMAs + 2x kern21.
// (f16 accuracy validated end-to-end in R12/R13.)
__device__ __forceinline__ void doc_step2(
    half8 A0, half8 A1, half8 B0, half8 B1, f32x2* acc)
{
    f32x4 C = {0.f, 0.f, 0.f, 0.f};
    C = __builtin_amdgcn_mfma_f32_16x16x32_f16(A0, B0, C, 0, 0, 0);
    C = __builtin_amdgcn_mfma_f32_16x16x32_f16(A1, B1, C, 0, 0, 0);
    f32x2 a01 = {C[0], C[1]};
    f32x2 a23 = {C[2], C[3]};
    kern21(a01, acc);
    kern21(a23, acc);
}

// ---- prep: normalize (f32) + convert to f16; 64 f16 = 128 B per token ----
// layout: wse[tok*8 + c] = chunk c (8 f16), elements 50..63 zero.
__global__ __launch_bounds__(256) void knrm_prep_kernel(
    const float* __restrict__ emb, uint4* __restrict__ wse, int vocab)
{
    const int tid = threadIdx.x;
    const int row = blockIdx.x * 32 + (tid >> 3);
    const int cb  = tid & 7;
    if (row >= vocab) return;   // whole 8-lane group exits together

    const float* src = emb + (size_t)row * 50;
    float v[8];
    float ss = 0.f;
    #pragma unroll
    for (int p = 0; p < 4; ++p) {
        int e = cb * 8 + 2 * p;
        float2 t;
        if (e + 2 <= 50) t = *(const float2*)(src + e);
        else             t = make_float2(0.f, 0.f);
        v[2*p]   = t.x;
        v[2*p+1] = t.y;
        ss = fmaf(t.x, t.x, fmaf(t.y, t.y, ss));
    }
    ss += __shfl_xor(ss, 1, 64);
    ss += __shfl_xor(ss, 2, 64);
    ss += __shfl_xor(ss, 4, 64);
    float rn = __builtin_amdgcn_rsqf(ss);

    half8 hv;
    #pragma unroll
    for (int p = 0; p < 8; ++p) hv[p] = (_Float16)(v[p] * rn);
    wse[(size_t)row * 8 + cb] = __builtin_bit_cast(uint4, hv);
}

__device__ __forceinline__ half8 frag_ldh(const uint4* mat, int row, int chunk)
{
    return __builtin_bit_cast(half8, mat[row * 8 + (chunk ^ (row & 7))]);
}

// ==== main pass kernel (PRE): wave-private pipeline, single-fetch docs ====
// Block = (batch, pass), 4 waves = (qtile = w>>1) x (dhalf = w&1). Each wave
// owns its doc QUARTER-VIEW (qtile x 256 docs) and a PRIVATE 8 KB LDS double
// buffer: 8 chunks x 32 rows, staged via 4 glds/chunk (linear dest +
// pre-swizzled source, rule #21), per-wave s_waitcnt vmcnt(0) (R10-validated)
// -- ZERO main-loop barriers, no 4-wave convoy. qtile-twin waves gather the
// same doc rows near-simultaneously -> L1/L2 absorbs the duplicate demand
// (HBM single-fetch, unlike R10's cross-block split). B-frags per-lane from
// global (R6-validated). One __syncthreads at the fold.
__global__ __launch_bounds__(256, 4) void knrm_pass_pre(
    const int* __restrict__ q1, const int* __restrict__ d1,
    const int* __restrict__ q2, const int* __restrict__ d2,
    const uint4* __restrict__ wse, const float* __restrict__ mlp_w,
    float* __restrict__ ws_logit)
{
    __shared__ uint4 dbuf[4][2][256];   // 32 KB: [wave][buf][row*8 + slot]
    __shared__ float Swk[4][21][16];
    __shared__ float wred[4];

    const int tid  = threadIdx.x;
    const int bx   = blockIdx.x;        // b*2 + pass
    const int b    = bx >> 1;
    const int lane = tid & 63;
    const int wave = tid >> 6;          // qt = wave>>1, dh = wave&1
    const int g    = lane >> 4;         // k-group 0..3

    const int* qidx = ((bx & 1) ? q2 : q1) + b * 32;
    const int* dd   = ((bx & 1) ? d2 : d1) + b * 512 + (wave & 1) * 256;

    // ---- B fragments per-lane direct from global ----
    const int qrow = (wave >> 1) * 16 + (lane & 15);
    const uint4* qb = wse + (size_t)qidx[qrow] * 8;
    half8 B0 = __builtin_bit_cast(half8, qb[g]);
    half8 B1 = __builtin_bit_cast(half8, qb[4 + g]);

    const int rsub = lane >> 3;         // staging sub-row 0..7
    const int swz  = (lane & 7) ^ rsub; // pre-swizzled source chunk

    uint4* buf0 = dbuf[wave][0];
    uint4* buf1 = dbuf[wave][1];

    // ---- prologue: chunk 0 -> buf0; tokens for chunk 1 ----
    int t0 = dd[rsub], t1 = dd[8 + rsub], t2 = dd[16 + rsub], t3 = dd[24 + rsub];
    glds16(wse + (size_t)t0 * 8 + swz, buf0);
    glds16(wse + (size_t)t1 * 8 + swz, buf0 + 64);
    glds16(wse + (size_t)t2 * 8 + swz, buf0 + 128);
    glds16(wse + (size_t)t3 * 8 + swz, buf0 + 192);
    t0 = dd[32 + rsub]; t1 = dd[40 + rsub]; t2 = dd[48 + rsub]; t3 = dd[56 + rsub];

    f32x2 acc2[21];
    #pragma unroll
    for (int k = 0; k < 21; ++k) acc2[k] = (f32x2){0.f, 0.f};

    const int ar0 = lane & 15;          // rows 0..15 of chunk
    const int ar1 = 16 + ar0;           // rows 16..31

    for (int c = 0; c < 8; ++c) {
        // wait: chunk c's glds landed (wave-private; tokens also retired)
        asm volatile("s_waitcnt vmcnt(0)" ::: "memory");
        __builtin_amdgcn_sched_barrier(0);

        uint4* cur = (c & 1) ? buf1 : buf0;
        uint4* nxt = (c & 1) ? buf0 : buf1;

        // issue next chunk's staging into the other private buffer
        if (c < 7) {
            glds16(wse + (size_t)t0 * 8 + swz, nxt);
            glds16(wse + (size_t)t1 * 8 + swz, nxt + 64);
            glds16(wse + (size_t)t2 * 8 + swz, nxt + 128);
            glds16(wse + (size_t)t3 * 8 + swz, nxt + 192);
            if (c < 6) {
                t0 = dd[(c + 2) * 32 + rsub];
                t1 = dd[(c + 2) * 32 + 8 + rsub];
                t2 = dd[(c + 2) * 32 + 16 + rsub];
                t3 = dd[(c + 2) * 32 + 24 + rsub];
            }
        }

        // compute chunk c (glds(c+1) latency hides under it)
        doc_step2(frag_ldh(cur, ar0, g), frag_ldh(cur, ar0, 4 + g), B0, B1, acc2);
        doc_step2(frag_ldh(cur, ar1, g), frag_ldh(cur, ar1, 4 + g), B0, B1, acc2);
    }

    // ---- fold packed pair + the 4 doc-row groups of this wave ----
    float acc[21];
    #pragma unroll
    for (int k = 0; k < 21; ++k) {
        float v = acc2[k].x + acc2[k].y;
        v += __shfl_xor(v, 16, 64);
        v += __shfl_xor(v, 32, 64);
        acc[k] = v;
    }
    if (lane < 16) {
        #pragma unroll
        for (int k = 0; k < 21; ++k) Swk[wave][k][lane] = acc[k];
    }
    __syncthreads();   // the ONLY block barrier

    // ---- log1p + deferred c_j scale + weights; block reduction ----
    // waves {0,1} = qtile0 (dh 0,1), {2,3} = qtile1 -> wp = (q>>4)*2 sums
    // the two doc-halves of q's tile (same mapping as R13, verified).
    float local = 0.f;
    for (int p = tid; p < 21 * 32; p += 256) {
        int k = p >> 5, q = p & 31;
        int wp = (q >> 4) * 2;
        float S = Swk[wp][k][q & 15] + Swk[wp + 1][k][q & 15];
        float j = (float)(k - 9);
        float scale = (k < 20) ? fexp2(-0.7213475204444817f * j * j) : 1.0f;
        local += mlp_w[k] * log1pf(S * scale);
    }
    #pragma unroll
    for (int off = 1; off < 64; off <<= 1) local += __shfl_xor(local, off, 64);
    if (lane == 0) wred[wave] = local;
    __syncthreads();
    if (tid == 0)
        ws_logit[bx] = wred[0] + wred[1] + wred[2] + wred[3];  // bias cancels
}

// ==== fallback (ws too small): R2-proven bf16 hi/lo self-contained path ====
__device__ __forceinline__ short8 frag_ldb(const uint4* mat, int row, int chunk)
{
    return __builtin_bit_cast(short8, mat[row * 8 + (chunk ^ (row & 7))]);
}

__device__ __forceinline__ void doc_step_fb(
    short8 Ah0, short8 Ah1, short8 Al0, short8 Al1,
    short8 Bh0, short8 Bh1, short8 Bl0, short8 Bl1, f32x2* acc)
{
    f32x4 C = {0.f, 0.f, 0.f, 0.f};
    C = __builtin_amdgcn_mfma_f32_16x16x32_bf16(Ah0, Bh0, C, 0, 0, 0);
    C = __builtin_amdgcn_mfma_f32_16x16x32_bf16(Ah1, Bh1, C, 0, 0, 0);
    C = __builtin_amdgcn_mfma_f32_16x16x32_bf16(Ah0, Bl0, C, 0, 0, 0);
    C = __builtin_amdgcn_mfma_f32_16x16x32_bf16(Ah1, Bl1, C, 0, 0, 0);
    C = __builtin_amdgcn_mfma_f32_16x16x32_bf16(Al0, Bh0, C, 0, 0, 0);
    C = __builtin_amdgcn_mfma_f32_16x16x32_bf16(Al1, Bh1, C, 0, 0, 0);
    f32x2 a01 = {C[0], C[1]};
    f32x2 a23 = {C[2], C[3]};
    kern21(a01, acc);
    kern21(a23, acc);
}

__device__ __forceinline__ void stage_row_chunk(
    const float* __restrict__ emb, int tok, int row, int cb,
    uint4* __restrict__ hmat, uint4* __restrict__ lmat)
{
    const float* src = emb + (size_t)tok * 50;
    float v[8];
    float ss = 0.f;
    #pragma unroll
    for (int p = 0; p < 4; ++p) {
        int e = cb * 8 + 2 * p;
        float2 t;
        if (e + 2 <= 50) t = *(const float2*)(src + e);
        else             t = make_float2(0.f, 0.f);
        v[2*p]   = t.x;
        v[2*p+1] = t.y;
        ss = fmaf(t.x, t.x, fmaf(t.y, t.y, ss));
    }
    ss += __shfl_xor(ss, 1, 64);
    ss += __shfl_xor(ss, 2, 64);
    ss += __shfl_xor(ss, 4, 64);
    float rn = __builtin_amdgcn_rsqf(ss);

    unsigned hw[4], lw[4];
    #pragma unroll
    for (int p = 0; p < 4; ++p) {
        float a = v[2*p]   * rn;
        float b = v[2*p+1] * rn;
        unsigned ha = __float_as_uint(a) & 0xFFFF0000u;
        unsigned hb = __float_as_uint(b) & 0xFFFF0000u;
        float la = a - __uint_as_float(ha);
        float lb = b - __uint_as_float(hb);
        hw[p] = (ha >> 16) | hb;
        lw[p] = (__float_as_uint(la) >> 16) | (__float_as_uint(lb) & 0xFFFF0000u);
    }
    int cidx = cb ^ (row & 7);
    hmat[row * 8 + cidx] = make_uint4(hw[0], hw[1], hw[2], hw[3]);
    lmat[row * 8 + cidx] = make_uint4(lw[0], lw[1], lw[2], lw[3]);
}

__global__ __launch_bounds__(256, 4) void knrm_pass_fb(
    const int* __restrict__ q1, const int* __restrict__ d1,
    const int* __restrict__ q2, const int* __restrict__ d2,
    const float* __restrict__ emb, const float* __restrict__ mlp_w,
    float* __restrict__ ws_logit)
{
    __shared__ uint4 qh4[256], ql4[256];
    __shared__ uint4 dh4[256], dl4[256];
    __shared__ float Swk[4][21][16];
    __shared__ float wred[4];

    const int tid  = threadIdx.x;
    const int bx   = blockIdx.x;
    const int b    = bx >> 1;
    const int lane = tid & 63;
    const int wave = tid >> 6;
    const int g    = lane >> 4;

    const int* qidx = ((bx & 1) ? q2 : q1) + b * 32;
    const int* didx = ((bx & 1) ? d2 : d1) + b * 512;

    const int srow = tid >> 3;
    const int scb  = tid & 7;

    stage_row_chunk(emb, qidx[srow], srow, scb, qh4, ql4);
    __syncthreads();

    const int qrow = (wave >> 1) * 16 + (lane & 15);
    short8 Bh0 = frag_ldb(qh4, qrow, g);
    short8 Bh1 = frag_ldb(qh4, qrow, 4 + g);
    short8 Bl0 = frag_ldb(ql4, qrow, g);
    short8 Bl1 = frag_ldb(ql4, qrow, 4 + g);

    f32x2 acc2[21];
    #pragma unroll
    for (int k = 0; k < 21; ++k) acc2[k] = (f32x2){0.f, 0.f};

    const int arow = (wave & 1) * 16 + (lane & 15);

    for (int c = 0; c < 16; ++c) {
        if (c) __syncthreads();
        stage_row_chunk(emb, didx[c * 32 + srow], srow, scb, dh4, dl4);
        __syncthreads();
        doc_step_fb(frag_ldb(dh4, arow, g), frag_ldb(dh4, arow, 4 + g),
                    frag_ldb(dl4, arow, g), frag_ldb(dl4, arow, 4 + g),
                    Bh0, Bh1, Bl0, Bl1, acc2);
    }
    __syncthreads();

    float acc[21];
    #pragma unroll
    for (int k = 0; k < 21; ++k) {
        float v = acc2[k].x + acc2[k].y;
        v += __shfl_xor(v, 16, 64);
        v += __shfl_xor(v, 32, 64);
        acc[k] = v;
    }
    if (lane < 16) {
        #pragma unroll
        for (int k = 0; k < 21; ++k) Swk[wave][k][lane] = acc[k];
    }
    __syncthreads();

    float local = 0.f;
    for (int p = tid; p < 21 * 32; p += 256) {
        int k = p >> 5, q = p & 31;
        int wp = (q >> 4) * 2;
        float S = Swk[wp][k][q & 15] + Swk[wp + 1][k][q & 15];
        float j = (float)(k - 9);
        float scale = (k < 20) ? fexp2(-0.7213475204444817f * j * j) : 1.0f;
        local += mlp_w[k] * log1pf(S * scale);
    }
    #pragma unroll
    for (int off = 1; off < 64; off <<= 1) local += __shfl_xor(local, off, 64);
    if (lane == 0) wred[wave] = local;
    __syncthreads();
    if (tid == 0)
        ws_logit[bx] = wred[0] + wred[1] + wred[2] + wred[3];
}

__global__ void knrm_final_kernel(const float* __restrict__ P,
                                  float* __restrict__ out, int B)
{
    int i = blockIdx.x * 256 + threadIdx.x;
    if (i < B) {
        float x = P[2 * i] - P[2 * i + 1];
        out[i] = 1.0f / (1.0f + fexp2(-LOG2E * x));
    }
}

extern "C" void kernel_launch(void* const* d_in, const int* in_sizes, int n_in,
                              void* d_out, int out_size, void* d_ws, size_t ws_size,
                              hipStream_t stream) {
    const int*   q1    = (const int*)d_in[0];
    const int*   d1    = (const int*)d_in[1];
    const int*   q2    = (const int*)d_in[2];
    const int*   d2    = (const int*)d_in[3];
    const float* emb   = (const float*)d_in[4];
    const float* mlp_w = (const float*)d_in[5];
    float*       out   = (float*)d_out;

    const int B     = out_size;            // 1024
    const int vocab = in_sizes[4] / 50;    // 100000

    float* ws_logit = (float*)d_ws;                       // 2*B floats = 8192 B
    uint4* wse      = (uint4*)((char*)d_ws + 8192);       // f16 embeddings
    size_t need     = 8192 + (size_t)vocab * 128;

    if (ws_size >= need) {
        knrm_prep_kernel<<<dim3((vocab + 31) / 32), dim3(256), 0, stream>>>(emb, wse, vocab);
        knrm_pass_pre<<<dim3(2 * B), dim3(256), 0, stream>>>(
            q1, d1, q2, d2, wse, mlp_w, ws_logit);
    } else {
        knrm_pass_fb<<<dim3(2 * B), dim3(256), 0, stream>>>(
            q1, d1, q2, d2, emb, mlp_w, ws_logit);
    }
    knrm_final_kernel<<<dim3((B + 255) / 256), dim3(256), 0, stream>>>(ws_logit, out, B);
}

// Round 18
// 60.691 us; speedup vs baseline: 1.0677x; 1.0113x over previous
//
#include <hip/hip_runtime.h>
#include <math.h>

#define LOG2E 1.4426950408889634f

typedef __attribute__((ext_vector_type(8))) short    short8;   // 8 bf16
typedef __attribute__((ext_vector_type(8))) _Float16 half8;    // 8 f16 (4 VGPR)
typedef __attribute__((ext_vector_type(4))) float    f32x4;    // MFMA C/D
typedef __attribute__((ext_vector_type(2))) float    f32x2;    // packed pair

__device__ __forceinline__ float fexp2(float x) { return __builtin_amdgcn_exp2f(x); }

// async global->LDS, 16B/lane: LDS dest = wave-uniform base + lane*16;
// per-lane global source; offset immediate ALWAYS 0 (R9/R10 lesson).
typedef __attribute__((address_space(1))) const unsigned int gas_u32;
typedef __attribute__((address_space(3))) unsigned int las_u32;
__device__ __forceinline__ void glds16(const uint4* g, uint4* l)
{ __builtin_amdgcn_global_load_lds((gas_u32*)g, (las_u32*)l, 16, 0, 0); }

// 21 Gaussian kernels for 2 sims -> acc[21] (f32x2), DEFERRED normalization
// (validated R6-R17): g_{9+j}(s) = gc * v^j * e^{-j^2/2}, v = e^{10s+0.5},
// gc = e^{-50(s+0.05)^2}; c_j applied at the fold. Exact kernel (mu=1,
// sigma=0.001) via guarded FP path (wave-uniform skip, ~0.1% taken).
__device__ __forceinline__ void kern21(f32x2 s, f32x2* acc)
{
    s.x = __builtin_amdgcn_fmed3f(s.x, -1.1f, 1.1f);
    s.y = __builtin_amdgcn_fmed3f(s.y, -1.1f, 1.1f);

    f32x2 va = s * 14.426950408889634f + 0.7213475204444817f;  // log2(e)*(10s+0.5)
    f32x2 v, vi, gc;
    v.x  = fexp2(va.x);  v.y  = fexp2(va.y);
    vi.x = __builtin_amdgcn_rcpf(v.x);
    vi.y = __builtin_amdgcn_rcpf(v.y);
    f32x2 t9 = s + 0.05f;
    f32x2 ga = (t9 * t9) * -72.13475204444817f;                // -50/ln2
    gc.x = fexp2(ga.x);  gc.y = fexp2(ga.y);

    f32x2 p = gc;
    acc[9] += p;
    #pragma unroll
    for (int k = 10; k <= 19; ++k) { p *= v; acc[k] += p; }    // up: j=1..10
    f32x2 q = gc;
    #pragma unroll
    for (int k = 8; k >= 0; --k) { q *= vi; acc[k] += q; }     // down: j=1..9
    if (__any(fmaxf(s.x, s.y) > 0.995f)) {
        f32x2 te = s - 1.0f;
        f32x2 ea = (te * te) * -721347.5204444817f;
        f32x2 ge; ge.x = fexp2(ea.x); ge.y = fexp2(ea.y);
        acc[20] += ge;
    }
}

// MFMA half of a 16x16 tile (f16 single, validated R12/R13).
__device__ __forceinline__ f32x4 mfma2(half8 A0, half8 A1, half8 B0, half8 B1)
{
    f32x4 C = {0.f, 0.f, 0.f, 0.f};
    C = __builtin_amdgcn_mfma_f32_16x16x32_f16(A0, B0, C, 0, 0, 0);
    C = __builtin_amdgcn_mfma_f32_16x16x32_f16(A1, B1, C, 0, 0, 0);
    return C;
}

// kern21 half: evaluate 2 tiles' worth of sims (4 packed pairs).
__device__ __forceinline__ void kern4(f32x4 C0, f32x4 C1, f32x2* acc)
{
    f32x2 a, b;
    a.x = C0[0]; a.y = C0[1]; kern21(a, acc);
    b.x = C0[2]; b.y = C0[3]; kern21(b, acc);
    a.x = C1[0]; a.y = C1[1]; kern21(a, acc);
    b.x = C1[2]; b.y = C1[3]; kern21(b, acc);
}

// ---- prep: normalize (f32) + convert to f16; 64 f16 = 128 B per token ----
__global__ __launch_bounds__(256) void knrm_prep_kernel(
    const float* __restrict__ emb, uint4* __restrict__ wse, int vocab)
{
    const int tid = threadIdx.x;
    const int row = blockIdx.x * 32 + (tid >> 3);
    const int cb  = tid & 7;
    if (row >= vocab) return;   // whole 8-lane group exits together

    const float* src = emb + (size_t)row * 50;
    float v[8];
    float ss = 0.f;
    #pragma unroll
    for (int p = 0; p < 4; ++p) {
        int e = cb * 8 + 2 * p;
        float2 t;
        if (e + 2 <= 50) t = *(const float2*)(src + e);
        else             t = make_float2(0.f, 0.f);
        v[2*p]   = t.x;
        v[2*p+1] = t.y;
        ss = fmaf(t.x, t.x, fmaf(t.y, t.y, ss));
    }
    ss += __shfl_xor(ss, 1, 64);
    ss += __shfl_xor(ss, 2, 64);
    ss += __shfl_xor(ss, 4, 64);
    float rn = __builtin_amdgcn_rsqf(ss);

    half8 hv;
    #pragma unroll
    for (int p = 0; p < 8; ++p) hv[p] = (_Float16)(v[p] * rn);
    wse[(size_t)row * 8 + cb] = __builtin_bit_cast(uint4, hv);
}

__device__ __forceinline__ half8 frag_ldh(const uint4* mat, int row, int chunk)
{
    return __builtin_bit_cast(half8, mat[row * 8 + (chunk ^ (row & 7))]);
}

// ==== main pass kernel (PRE): R17 wave-private pipeline + MFMA/kern21
// one-stage software pipeline. Per iter: [vmcnt(0)] -> ds_read frags(c) ->
// issue glds(c+1) -> kern21 on C_prev (hides ~120cyc LDS latency + glds
// flight under ~1300cyc of independent VALU) -> sched_barrier -> MFMA(c).
// The lgkm wait before MFMA lands after the kern21 block -> zero exposed
// latency. +8 VGPR (2x f32x4 held across iters). Everything else R17.
__global__ __launch_bounds__(256, 4) void knrm_pass_pre(
    const int* __restrict__ q1, const int* __restrict__ d1,
    const int* __restrict__ q2, const int* __restrict__ d2,
    const uint4* __restrict__ wse, const float* __restrict__ mlp_w,
    float* __restrict__ ws_logit)
{
    __shared__ uint4 dbuf[4][2][256];   // 32 KB: [wave][buf][row*8 + slot]
    __shared__ float Swk[4][21][16];
    __shared__ float wred[4];

    const int tid  = threadIdx.x;
    const int bx   = blockIdx.x;        // b*2 + pass
    const int b    = bx >> 1;
    const int lane = tid & 63;
    const int wave = tid >> 6;          // qt = wave>>1, dh = wave&1
    const int g    = lane >> 4;         // k-group 0..3

    const int* qidx = ((bx & 1) ? q2 : q1) + b * 32;
    const int* dd   = ((bx & 1) ? d2 : d1) + b * 512 + (wave & 1) * 256;

    // ---- B fragments per-lane direct from global ----
    const int qrow = (wave >> 1) * 16 + (lane & 15);
    const uint4* qb = wse + (size_t)qidx[qrow] * 8;
    half8 B0 = __builtin_bit_cast(half8, qb[g]);
    half8 B1 = __builtin_bit_cast(half8, qb[4 + g]);

    const int rsub = lane >> 3;         // staging sub-row 0..7
    const int swz  = (lane & 7) ^ rsub; // pre-swizzled source chunk

    uint4* buf0 = dbuf[wave][0];
    uint4* buf1 = dbuf[wave][1];

    // ---- prologue: chunk 0 -> buf0; tokens for chunk 1 ----
    int t0 = dd[rsub], t1 = dd[8 + rsub], t2 = dd[16 + rsub], t3 = dd[24 + rsub];
    glds16(wse + (size_t)t0 * 8 + swz, buf0);
    glds16(wse + (size_t)t1 * 8 + swz, buf0 + 64);
    glds16(wse + (size_t)t2 * 8 + swz, buf0 + 128);
    glds16(wse + (size_t)t3 * 8 + swz, buf0 + 192);
    t0 = dd[32 + rsub]; t1 = dd[40 + rsub]; t2 = dd[48 + rsub]; t3 = dd[56 + rsub];

    f32x2 acc2[21];
    #pragma unroll
    for (int k = 0; k < 21; ++k) acc2[k] = (f32x2){0.f, 0.f};

    const int ar0 = lane & 15;          // rows 0..15 of chunk
    const int ar1 = 16 + ar0;           // rows 16..31

    // ---- pipeline prologue: chunk 0 MFMA -> Cp ----
    asm volatile("s_waitcnt vmcnt(0)" ::: "memory");
    __builtin_amdgcn_sched_barrier(0);
    f32x4 Cp0, Cp1;
    {
        half8 A00 = frag_ldh(buf0, ar0, g), A01 = frag_ldh(buf0, ar0, 4 + g);
        half8 A10 = frag_ldh(buf0, ar1, g), A11 = frag_ldh(buf0, ar1, 4 + g);
        // issue chunk 1 staging; tokens for chunk 2
        glds16(wse + (size_t)t0 * 8 + swz, buf1);
        glds16(wse + (size_t)t1 * 8 + swz, buf1 + 64);
        glds16(wse + (size_t)t2 * 8 + swz, buf1 + 128);
        glds16(wse + (size_t)t3 * 8 + swz, buf1 + 192);
        t0 = dd[64 + rsub]; t1 = dd[72 + rsub]; t2 = dd[80 + rsub]; t3 = dd[88 + rsub];
        Cp0 = mfma2(A00, A01, B0, B1);
        Cp1 = mfma2(A10, A11, B0, B1);
    }

    // ---- main loop: chunks 1..7; kern21 runs one chunk behind MFMA ----
    for (int c = 1; c < 8; ++c) {
        asm volatile("s_waitcnt vmcnt(0)" ::: "memory");
        __builtin_amdgcn_sched_barrier(0);

        uint4* cur = (c & 1) ? buf1 : buf0;
        uint4* nxt = (c & 1) ? buf0 : buf1;

        // ds_read frags for chunk c (latency hides under kern4 below)
        half8 A00 = frag_ldh(cur, ar0, g), A01 = frag_ldh(cur, ar0, 4 + g);
        half8 A10 = frag_ldh(cur, ar1, g), A11 = frag_ldh(cur, ar1, 4 + g);

        // issue next chunk's staging (flies under kern4 too)
        if (c < 7) {
            glds16(wse + (size_t)t0 * 8 + swz, nxt);
            glds16(wse + (size_t)t1 * 8 + swz, nxt + 64);
            glds16(wse + (size_t)t2 * 8 + swz, nxt + 128);
            glds16(wse + (size_t)t3 * 8 + swz, nxt + 192);
            if (c < 6) {
                t0 = dd[(c + 2) * 32 + rsub];
                t1 = dd[(c + 2) * 32 + 8 + rsub];
                t2 = dd[(c + 2) * 32 + 16 + rsub];
                t3 = dd[(c + 2) * 32 + 24 + rsub];
            }
        }

        // evaluate PREVIOUS chunk's sims (pure VALU, ~1300 cyc)
        kern4(Cp0, Cp1, acc2);

        // keep MFMA after kern4 (don't let scheduler hoist it into the window)
        __builtin_amdgcn_sched_barrier(0);
        Cp0 = mfma2(A00, A01, B0, B1);
        Cp1 = mfma2(A10, A11, B0, B1);
    }
    // ---- pipeline epilogue: chunk 7's sims ----
    kern4(Cp0, Cp1, acc2);

    // ---- fold packed pair + the 4 doc-row groups of this wave ----
    float acc[21];
    #pragma unroll
    for (int k = 0; k < 21; ++k) {
        float v = acc2[k].x + acc2[k].y;
        v += __shfl_xor(v, 16, 64);
        v += __shfl_xor(v, 32, 64);
        acc[k] = v;
    }
    if (lane < 16) {
        #pragma unroll
        for (int k = 0; k < 21; ++k) Swk[wave][k][lane] = acc[k];
    }
    __syncthreads();   // the ONLY block barrier

    // ---- log1p + deferred c_j scale + weights; block reduction ----
    float local = 0.f;
    for (int p = tid; p < 21 * 32; p += 256) {
        int k = p >> 5, q = p & 31;
        int wp = (q >> 4) * 2;
        float S = Swk[wp][k][q & 15] + Swk[wp + 1][k][q & 15];
        float j = (float)(k - 9);
        float scale = (k < 20) ? fexp2(-0.7213475204444817f * j * j) : 1.0f;
        local += mlp_w[k] * log1pf(S * scale);
    }
    #pragma unroll
    for (int off = 1; off < 64; off <<= 1) local += __shfl_xor(local, off, 64);
    if (lane == 0) wred[wave] = local;
    __syncthreads();
    if (tid == 0)
        ws_logit[bx] = wred[0] + wred[1] + wred[2] + wred[3];  // bias cancels
}

// ==== fallback (ws too small): R2-proven bf16 hi/lo self-contained path ====
__device__ __forceinline__ short8 frag_ldb(const uint4* mat, int row, int chunk)
{
    return __builtin_bit_cast(short8, mat[row * 8 + (chunk ^ (row & 7))]);
}

__device__ __forceinline__ void doc_step_fb(
    short8 Ah0, short8 Ah1, short8 Al0, short8 Al1,
    short8 Bh0, short8 Bh1, short8 Bl0, short8 Bl1, f32x2* acc)
{
    f32x4 C = {0.f, 0.f, 0.f, 0.f};
    C = __builtin_amdgcn_mfma_f32_16x16x32_bf16(Ah0, Bh0, C, 0, 0, 0);
    C = __builtin_amdgcn_mfma_f32_16x16x32_bf16(Ah1, Bh1, C, 0, 0, 0);
    C = __builtin_amdgcn_mfma_f32_16x16x32_bf16(Ah0, Bl0, C, 0, 0, 0);
    C = __builtin_amdgcn_mfma_f32_16x16x32_bf16(Ah1, Bl1, C, 0, 0, 0);
    C = __builtin_amdgcn_mfma_f32_16x16x32_bf16(Al0, Bh0, C, 0, 0, 0);
    C = __builtin_amdgcn_mfma_f32_16x16x32_bf16(Al1, Bh1, C, 0, 0, 0);
    f32x2 a01; a01.x = C[0]; a01.y = C[1];
    f32x2 a23; a23.x = C[2]; a23.y = C[3];
    kern21(a01, acc);
    kern21(a23, acc);
}

__device__ __forceinline__ void stage_row_chunk(
    const float* __restrict__ emb, int tok, int row, int cb,
    uint4* __restrict__ hmat, uint4* __restrict__ lmat)
{
    const float* src = emb + (size_t)tok * 50;
    float v[8];
    float ss = 0.f;
    #pragma unroll
    for (int p = 0; p < 4; ++p) {
        int e = cb * 8 + 2 * p;
        float2 t;
        if (e + 2 <= 50) t = *(const float2*)(src + e);
        else             t = make_float2(0.f, 0.f);
        v[2*p]   = t.x;
        v[2*p+1] = t.y;
        ss = fmaf(t.x, t.x, fmaf(t.y, t.y, ss));
    }
    ss += __shfl_xor(ss, 1, 64);
    ss += __shfl_xor(ss, 2, 64);
    ss += __shfl_xor(ss, 4, 64);
    float rn = __builtin_amdgcn_rsqf(ss);

    unsigned hw[4], lw[4];
    #pragma unroll
    for (int p = 0; p < 4; ++p) {
        float a = v[2*p]   * rn;
        float b = v[2*p+1] * rn;
        unsigned ha = __float_as_uint(a) & 0xFFFF0000u;
        unsigned hb = __float_as_uint(b) & 0xFFFF0000u;
        float la = a - __uint_as_float(ha);
        float lb = b - __uint_as_float(hb);
        hw[p] = (ha >> 16) | hb;
        lw[p] = (__float_as_uint(la) >> 16) | (__float_as_uint(lb) & 0xFFFF0000u);
    }
    int cidx = cb ^ (row & 7);
    hmat[row * 8 + cidx] = make_uint4(hw[0], hw[1], hw[2], hw[3]);
    lmat[row * 8 + cidx] = make_uint4(lw[0], lw[1], lw[2], lw[3]);
}

__global__ __launch_bounds__(256, 4) void knrm_pass_fb(
    const int* __restrict__ q1, const int* __restrict__ d1,
    const int* __restrict__ q2, const int* __restrict__ d2,
    const float* __restrict__ emb, const float* __restrict__ mlp_w,
    float* __restrict__ ws_logit)
{
    __shared__ uint4 qh4[256], ql4[256];
    __shared__ uint4 dh4[256], dl4[256];
    __shared__ float Swk[4][21][16];
    __shared__ float wred[4];

    const int tid  = threadIdx.x;
    const int bx   = blockIdx.x;
    const int b    = bx >> 1;
    const int lane = tid & 63;
    const int wave = tid >> 6;
    const int g    = lane >> 4;

    const int* qidx = ((bx & 1) ? q2 : q1) + b * 32;
    const int* didx = ((bx & 1) ? d2 : d1) + b * 512;

    const int srow = tid >> 3;
    const int scb  = tid & 7;

    stage_row_chunk(emb, qidx[srow], srow, scb, qh4, ql4);
    __syncthreads();

    const int qrow = (wave >> 1) * 16 + (lane & 15);
    short8 Bh0 = frag_ldb(qh4, qrow, g);
    short8 Bh1 = frag_ldb(qh4, qrow, 4 + g);
    short8 Bl0 = frag_ldb(ql4, qrow, g);
    short8 Bl1 = frag_ldb(ql4, qrow, 4 + g);

    f32x2 acc2[21];
    #pragma unroll
    for (int k = 0; k < 21; ++k) acc2[k] = (f32x2){0.f, 0.f};

    const int arow = (wave & 1) * 16 + (lane & 15);

    for (int c = 0; c < 16; ++c) {
        if (c) __syncthreads();
        stage_row_chunk(emb, didx[c * 32 + srow], srow, scb, dh4, dl4);
        __syncthreads();
        doc_step_fb(frag_ldb(dh4, arow, g), frag_ldb(dh4, arow, 4 + g),
                    frag_ldb(dl4, arow, g), frag_ldb(dl4, arow, 4 + g),
                    Bh0, Bh1, Bl0, Bl1, acc2);
    }
    __syncthreads();

    float acc[21];
    #pragma unroll
    for (int k = 0; k < 21; ++k) {
        float v = acc2[k].x + acc2[k].y;
        v += __shfl_xor(v, 16, 64);
        v += __shfl_xor(v, 32, 64);
        acc[k] = v;
    }
    if (lane < 16) {
        #pragma unroll
        for (int k = 0; k < 21; ++k) Swk[wave][k][lane] = acc[k];
    }
    __syncthreads();

    float local = 0.f;
    for (int p = tid; p < 21 * 32; p += 256) {
        int k = p >> 5, q = p & 31;
        int wp = (q >> 4) * 2;
        float S = Swk[wp][k][q & 15] + Swk[wp + 1][k][q & 15];
        float j = (float)(k - 9);
        float scale = (k < 20) ? fexp2(-0.7213475204444817f * j * j) : 1.0f;
        local += mlp_w[k] * log1pf(S * scale);
    }
    #pragma unroll
    for (int off = 1; off < 64; off <<= 1) local += __shfl_xor(local, off, 64);
    if (lane == 0) wred[wave] = local;
    __syncthreads();
    if (tid == 0)
        ws_logit[bx] = wred[0] + wred[1] + wred[2] + wred[3];
}

__global__ void knrm_final_kernel(const float* __restrict__ P,
                                  float* __restrict__ out, int B)
{
    int i = blockIdx.x * 256 + threadIdx.x;
    if (i < B) {
        float x = P[2 * i] - P[2 * i + 1];
        out[i] = 1.0f / (1.0f + fexp2(-LOG2E * x));
    }
}

extern "C" void kernel_launch(void* const* d_in, const int* in_sizes, int n_in,
                              void* d_out, int out_size, void* d_ws, size_t ws_size,
                              hipStream_t stream) {
    const int*   q1    = (const int*)d_in[0];
    const int*   d1    = (const int*)d_in[1];
    const int*   q2    = (const int*)d_in[2];
    const int*   d2    = (const int*)d_in[3];
    const float* emb   = (const float*)d_in[4];
    const float* mlp_w = (const float*)d_in[5];
    float*       out   = (float*)d_out;

    const int B     = out_size;            // 1024
    const int vocab = in_sizes[4] / 50;    // 100000

    float* ws_logit = (float*)d_ws;                       // 2*B floats = 8192 B
    uint4* wse      = (uint4*)((char*)d_ws + 8192);       // f16 embeddings
    size_t need     = 8192 + (size_t)vocab * 128;

    if (ws_size >= need) {
        knrm_prep_kernel<<<dim3((vocab + 31) / 32), dim3(256), 0, stream>>>(emb, wse, vocab);
        knrm_pass_pre<<<dim3(2 * B), dim3(256), 0, stream>>>(
            q1, d1, q2, d2, wse, mlp_w, ws_logit);
    } else {
        knrm_pass_fb<<<dim3(2 * B), dim3(256), 0, stream>>>(
            q1, d1, q2, d2, emb, mlp_w, ws_logit);
    }
    knrm_final_kernel<<<dim3((B + 255) / 256), dim3(256), 0, stream>>>(ws_logit, out, B);
}

// Round 19
// 60.471 us; speedup vs baseline: 1.0715x; 1.0036x over previous
//
#include <hip/hip_runtime.h>
#include <math.h>

#define LOG2E 1.4426950408889634f

typedef __attribute__((ext_vector_type(8))) short    short8;   // 8 bf16
typedef __attribute__((ext_vector_type(8))) _Float16 half8;    // 8 f16 (4 VGPR)
typedef __attribute__((ext_vector_type(4))) float    f32x4;    // MFMA C/D
typedef __attribute__((ext_vector_type(2))) float    f32x2;    // packed pair

__device__ __forceinline__ float fexp2(float x) { return __builtin_amdgcn_exp2f(x); }

// async global->LDS, 16B/lane: LDS dest = wave-uniform base + lane*16;
// per-lane global source; offset immediate ALWAYS 0 (R9/R10 lesson).
typedef __attribute__((address_space(1))) const unsigned int gas_u32;
typedef __attribute__((address_space(3))) unsigned int las_u32;
__device__ __forceinline__ void glds16(const uint4* g, uint4* l)
{ __builtin_amdgcn_global_load_lds((gas_u32*)g, (las_u32*)l, 16, 0, 0); }

// 21 Gaussian kernels for 2 sims -> acc[21] (f32x2), DEFERRED normalization
// (validated R6-R18): g_{9+j}(s) = gc * v^j * e^{-j^2/2}, v = e^{10s+0.5},
// gc = e^{-50(s+0.05)^2}; c_j applied at the fold. Exact kernel (mu=1,
// sigma=0.001) via guarded FP path (wave-uniform skip, ~0.1% taken).
__device__ __forceinline__ void kern21(f32x2 s, f32x2* acc)
{
    s.x = __builtin_amdgcn_fmed3f(s.x, -1.1f, 1.1f);
    s.y = __builtin_amdgcn_fmed3f(s.y, -1.1f, 1.1f);

    f32x2 va = s * 14.426950408889634f + 0.7213475204444817f;  // log2(e)*(10s+0.5)
    f32x2 v, vi, gc;
    v.x  = fexp2(va.x);  v.y  = fexp2(va.y);
    vi.x = __builtin_amdgcn_rcpf(v.x);
    vi.y = __builtin_amdgcn_rcpf(v.y);
    f32x2 t9 = s + 0.05f;
    f32x2 ga = (t9 * t9) * -72.13475204444817f;                // -50/ln2
    gc.x = fexp2(ga.x);  gc.y = fexp2(ga.y);

    f32x2 p = gc;
    acc[9] += p;
    #pragma unroll
    for (int k = 10; k <= 19; ++k) { p *= v; acc[k] += p; }    // up: j=1..10
    f32x2 q = gc;
    #pragma unroll
    for (int k = 8; k >= 0; --k) { q *= vi; acc[k] += q; }     // down: j=1..9
    if (__any(fmaxf(s.x, s.y) > 0.995f)) {
        f32x2 te = s - 1.0f;
        f32x2 ea = (te * te) * -721347.5204444817f;
        f32x2 ge; ge.x = fexp2(ea.x); ge.y = fexp2(ea.y);
        acc[20] += ge;
    }
}

// One 16x16 sim tile, f16 single-precision: 2 MFMAs + 2x kern21.
// (f16 accuracy validated end-to-end in R12/R13.)
__device__ __forceinline__ void doc_step2(
    half8 A0, half8 A1, half8 B0, half8 B1, f32x2* acc)
{
    f32x4 C = {0.f, 0.f, 0.f, 0.f};
    C = __builtin_amdgcn_mfma_f32_16x16x32_f16(A0, B0, C, 0, 0, 0);
    C = __builtin_amdgcn_mfma_f32_16x16x32_f16(A1, B1, C, 0, 0, 0);
    f32x2 a01; a01.x = C[0]; a01.y = C[1];
    f32x2 a23; a23.x = C[2]; a23.y = C[3];
    kern21(a01, acc);
    kern21(a23, acc);
}

// ---- prep: normalize (f32) + convert to f16; 64 f16 = 128 B per token ----
__global__ __launch_bounds__(256) void knrm_prep_kernel(
    const float* __restrict__ emb, uint4* __restrict__ wse, int vocab)
{
    const int tid = threadIdx.x;
    const int row = blockIdx.x * 32 + (tid >> 3);
    const int cb  = tid & 7;
    if (row >= vocab) return;   // whole 8-lane group exits together

    const float* src = emb + (size_t)row * 50;
    float v[8];
    float ss = 0.f;
    #pragma unroll
    for (int p = 0; p < 4; ++p) {
        int e = cb * 8 + 2 * p;
        float2 t;
        if (e + 2 <= 50) t = *(const float2*)(src + e);
        else             t = make_float2(0.f, 0.f);
        v[2*p]   = t.x;
        v[2*p+1] = t.y;
        ss = fmaf(t.x, t.x, fmaf(t.y, t.y, ss));
    }
    ss += __shfl_xor(ss, 1, 64);
    ss += __shfl_xor(ss, 2, 64);
    ss += __shfl_xor(ss, 4, 64);
    float rn = __builtin_amdgcn_rsqf(ss);

    half8 hv;
    #pragma unroll
    for (int p = 0; p < 8; ++p) hv[p] = (_Float16)(v[p] * rn);
    wse[(size_t)row * 8 + cb] = __builtin_bit_cast(uint4, hv);
}

__device__ __forceinline__ half8 frag_ldh(const uint4* mat, int row, int chunk)
{
    return __builtin_bit_cast(half8, mat[row * 8 + (chunk ^ (row & 7))]);
}

// ==== main pass kernel (PRE): R17 barrier-free wave-private pipeline with
// SMALL chunks (16 rows) to lift occupancy. LDS: dbuf 16 KB + Swk 5.4 KB ->
// ~21.5 KB/block -> 7 blocks/CU (28 waves) vs R17's 4 blocks @38 KB. The
// four scheduling nulls (R16-R18) showed intra-wave latency hiding is
// exhausted; remaining idle needs MORE WAVES. 16 chunks x {vmcnt(0) ->
// ds_read -> issue glds(c+1) -> 1 doc_step2}; per-wave sync only.
__global__ __launch_bounds__(256, 4) void knrm_pass_pre(
    const int* __restrict__ q1, const int* __restrict__ d1,
    const int* __restrict__ q2, const int* __restrict__ d2,
    const uint4* __restrict__ wse, const float* __restrict__ mlp_w,
    float* __restrict__ ws_logit)
{
    __shared__ uint4 dbuf[4][2][128];   // 16 KB: [wave][buf][row*8 + slot]
    __shared__ float Swk[4][21][16];
    __shared__ float wred[4];

    const int tid  = threadIdx.x;
    const int bx   = blockIdx.x;        // b*2 + pass
    const int b    = bx >> 1;
    const int lane = tid & 63;
    const int wave = tid >> 6;          // qt = wave>>1, dh = wave&1
    const int g    = lane >> 4;         // k-group 0..3

    const int* qidx = ((bx & 1) ? q2 : q1) + b * 32;
    const int* dd   = ((bx & 1) ? d2 : d1) + b * 512 + (wave & 1) * 256;

    // ---- B fragments per-lane direct from global ----
    const int qrow = (wave >> 1) * 16 + (lane & 15);
    const uint4* qb = wse + (size_t)qidx[qrow] * 8;
    half8 B0 = __builtin_bit_cast(half8, qb[g]);
    half8 B1 = __builtin_bit_cast(half8, qb[4 + g]);

    const int rsub = lane >> 3;         // staging sub-row 0..7
    const int swz  = (lane & 7) ^ rsub; // pre-swizzled source chunk

    uint4* buf0 = dbuf[wave][0];
    uint4* buf1 = dbuf[wave][1];

    // ---- prologue: chunk 0 (rows 0..15) -> buf0; tokens for chunk 1 ----
    int t0 = dd[rsub], t1 = dd[8 + rsub];
    glds16(wse + (size_t)t0 * 8 + swz, buf0);
    glds16(wse + (size_t)t1 * 8 + swz, buf0 + 64);
    t0 = dd[16 + rsub]; t1 = dd[24 + rsub];

    f32x2 acc2[21];
    #pragma unroll
    for (int k = 0; k < 21; ++k) acc2[k] = (f32x2){0.f, 0.f};

    const int ar0 = lane & 15;          // row in 16-row chunk

    for (int c = 0; c < 16; ++c) {
        // wait: chunk c's glds landed (wave-private)
        asm volatile("s_waitcnt vmcnt(0)" ::: "memory");
        __builtin_amdgcn_sched_barrier(0);

        uint4* cur = (c & 1) ? buf1 : buf0;
        uint4* nxt = (c & 1) ? buf0 : buf1;

        // issue next chunk's staging into the other private buffer
        if (c < 15) {
            glds16(wse + (size_t)t0 * 8 + swz, nxt);
            glds16(wse + (size_t)t1 * 8 + swz, nxt + 64);
            if (c < 14) {
                t0 = dd[(c + 2) * 16 + rsub];
                t1 = dd[(c + 2) * 16 + 8 + rsub];
            }
        }

        // compute chunk c (glds(c+1) latency hides under it + other waves)
        doc_step2(frag_ldh(cur, ar0, g), frag_ldh(cur, ar0, 4 + g), B0, B1, acc2);
    }

    // ---- fold packed pair + the 4 doc-row groups of this wave ----
    float acc[21];
    #pragma unroll
    for (int k = 0; k < 21; ++k) {
        float v = acc2[k].x + acc2[k].y;
        v += __shfl_xor(v, 16, 64);
        v += __shfl_xor(v, 32, 64);
        acc[k] = v;
    }
    if (lane < 16) {
        #pragma unroll
        for (int k = 0; k < 21; ++k) Swk[wave][k][lane] = acc[k];
    }
    __syncthreads();   // the ONLY block barrier

    // ---- log1p + deferred c_j scale + weights; block reduction ----
    // waves {0,1} = qtile0 (dh 0,1), {2,3} = qtile1 (mapping as R13/R17).
    float local = 0.f;
    for (int p = tid; p < 21 * 32; p += 256) {
        int k = p >> 5, q = p & 31;
        int wp = (q >> 4) * 2;
        float S = Swk[wp][k][q & 15] + Swk[wp + 1][k][q & 15];
        float j = (float)(k - 9);
        float scale = (k < 20) ? fexp2(-0.7213475204444817f * j * j) : 1.0f;
        local += mlp_w[k] * log1pf(S * scale);
    }
    #pragma unroll
    for (int off = 1; off < 64; off <<= 1) local += __shfl_xor(local, off, 64);
    if (lane == 0) wred[wave] = local;
    __syncthreads();
    if (tid == 0)
        ws_logit[bx] = wred[0] + wred[1] + wred[2] + wred[3];  // bias cancels
}

// ==== fallback (ws too small): R2-proven bf16 hi/lo self-contained path ====
__device__ __forceinline__ short8 frag_ldb(const uint4* mat, int row, int chunk)
{
    return __builtin_bit_cast(short8, mat[row * 8 + (chunk ^ (row & 7))]);
}

__device__ __forceinline__ void doc_step_fb(
    short8 Ah0, short8 Ah1, short8 Al0, short8 Al1,
    short8 Bh0, short8 Bh1, short8 Bl0, short8 Bl1, f32x2* acc)
{
    f32x4 C = {0.f, 0.f, 0.f, 0.f};
    C = __builtin_amdgcn_mfma_f32_16x16x32_bf16(Ah0, Bh0, C, 0, 0, 0);
    C = __builtin_amdgcn_mfma_f32_16x16x32_bf16(Ah1, Bh1, C, 0, 0, 0);
    C = __builtin_amdgcn_mfma_f32_16x16x32_bf16(Ah0, Bl0, C, 0, 0, 0);
    C = __builtin_amdgcn_mfma_f32_16x16x32_bf16(Ah1, Bl1, C, 0, 0, 0);
    C = __builtin_amdgcn_mfma_f32_16x16x32_bf16(Al0, Bh0, C, 0, 0, 0);
    C = __builtin_amdgcn_mfma_f32_16x16x32_bf16(Al1, Bh1, C, 0, 0, 0);
    f32x2 a01; a01.x = C[0]; a01.y = C[1];
    f32x2 a23; a23.x = C[2]; a23.y = C[3];
    kern21(a01, acc);
    kern21(a23, acc);
}

__device__ __forceinline__ void stage_row_chunk(
    const float* __restrict__ emb, int tok, int row, int cb,
    uint4* __restrict__ hmat, uint4* __restrict__ lmat)
{
    const float* src = emb + (size_t)tok * 50;
    float v[8];
    float ss = 0.f;
    #pragma unroll
    for (int p = 0; p < 4; ++p) {
        int e = cb * 8 + 2 * p;
        float2 t;
        if (e + 2 <= 50) t = *(const float2*)(src + e);
        else             t = make_float2(0.f, 0.f);
        v[2*p]   = t.x;
        v[2*p+1] = t.y;
        ss = fmaf(t.x, t.x, fmaf(t.y, t.y, ss));
    }
    ss += __shfl_xor(ss, 1, 64);
    ss += __shfl_xor(ss, 2, 64);
    ss += __shfl_xor(ss, 4, 64);
    float rn = __builtin_amdgcn_rsqf(ss);

    unsigned hw[4], lw[4];
    #pragma unroll
    for (int p = 0; p < 4; ++p) {
        float a = v[2*p]   * rn;
        float b = v[2*p+1] * rn;
        unsigned ha = __float_as_uint(a) & 0xFFFF0000u;
        unsigned hb = __float_as_uint(b) & 0xFFFF0000u;
        float la = a - __uint_as_float(ha);
        float lb = b - __uint_as_float(hb);
        hw[p] = (ha >> 16) | hb;
        lw[p] = (__float_as_uint(la) >> 16) | (__float_as_uint(lb) & 0xFFFF0000u);
    }
    int cidx = cb ^ (row & 7);
    hmat[row * 8 + cidx] = make_uint4(hw[0], hw[1], hw[2], hw[3]);
    lmat[row * 8 + cidx] = make_uint4(lw[0], lw[1], lw[2], lw[3]);
}

__global__ __launch_bounds__(256, 4) void knrm_pass_fb(
    const int* __restrict__ q1, const int* __restrict__ d1,
    const int* __restrict__ q2, const int* __restrict__ d2,
    const float* __restrict__ emb, const float* __restrict__ mlp_w,
    float* __restrict__ ws_logit)
{
    __shared__ uint4 qh4[256], ql4[256];
    __shared__ uint4 dh4[256], dl4[256];
    __shared__ float Swk[4][21][16];
    __shared__ float wred[4];

    const int tid  = threadIdx.x;
    const int bx   = blockIdx.x;
    const int b    = bx >> 1;
    const int lane = tid & 63;
    const int wave = tid >> 6;
    const int g    = lane >> 4;

    const int* qidx = ((bx & 1) ? q2 : q1) + b * 32;
    const int* didx = ((bx & 1) ? d2 : d1) + b * 512;

    const int srow = tid >> 3;
    const int scb  = tid & 7;

    stage_row_chunk(emb, qidx[srow], srow, scb, qh4, ql4);
    __syncthreads();

    const int qrow = (wave >> 1) * 16 + (lane & 15);
    short8 Bh0 = frag_ldb(qh4, qrow, g);
    short8 Bh1 = frag_ldb(qh4, qrow, 4 + g);
    short8 Bl0 = frag_ldb(ql4, qrow, g);
    short8 Bl1 = frag_ldb(ql4, qrow, 4 + g);

    f32x2 acc2[21];
    #pragma unroll
    for (int k = 0; k < 21; ++k) acc2[k] = (f32x2){0.f, 0.f};

    const int arow = (wave & 1) * 16 + (lane & 15);

    for (int c = 0; c < 16; ++c) {
        if (c) __syncthreads();
        stage_row_chunk(emb, didx[c * 32 + srow], srow, scb, dh4, dl4);
        __syncthreads();
        doc_step_fb(frag_ldb(dh4, arow, g), frag_ldb(dh4, arow, 4 + g),
                    frag_ldb(dl4, arow, g), frag_ldb(dl4, arow, 4 + g),
                    Bh0, Bh1, Bl0, Bl1, acc2);
    }
    __syncthreads();

    float acc[21];
    #pragma unroll
    for (int k = 0; k < 21; ++k) {
        float v = acc2[k].x + acc2[k].y;
        v += __shfl_xor(v, 16, 64);
        v += __shfl_xor(v, 32, 64);
        acc[k] = v;
    }
    if (lane < 16) {
        #pragma unroll
        for (int k = 0; k < 21; ++k) Swk[wave][k][lane] = acc[k];
    }
    __syncthreads();

    float local = 0.f;
    for (int p = tid; p < 21 * 32; p += 256) {
        int k = p >> 5, q = p & 31;
        int wp = (q >> 4) * 2;
        float S = Swk[wp][k][q & 15] + Swk[wp + 1][k][q & 15];
        float j = (float)(k - 9);
        float scale = (k < 20) ? fexp2(-0.7213475204444817f * j * j) : 1.0f;
        local += mlp_w[k] * log1pf(S * scale);
    }
    #pragma unroll
    for (int off = 1; off < 64; off <<= 1) local += __shfl_xor(local, off, 64);
    if (lane == 0) wred[wave] = local;
    __syncthreads();
    if (tid == 0)
        ws_logit[bx] = wred[0] + wred[1] + wred[2] + wred[3];
}

__global__ void knrm_final_kernel(const float* __restrict__ P,
                                  float* __restrict__ out, int B)
{
    int i = blockIdx.x * 256 + threadIdx.x;
    if (i < B) {
        float x = P[2 * i] - P[2 * i + 1];
        out[i] = 1.0f / (1.0f + fexp2(-LOG2E * x));
    }
}

extern "C" void kernel_launch(void* const* d_in, const int* in_sizes, int n_in,
                              void* d_out, int out_size, void* d_ws, size_t ws_size,
                              hipStream_t stream) {
    const int*   q1    = (const int*)d_in[0];
    const int*   d1    = (const int*)d_in[1];
    const int*   q2    = (const int*)d_in[2];
    const int*   d2    = (const int*)d_in[3];
    const float* emb   = (const float*)d_in[4];
    const float* mlp_w = (const float*)d_in[5];
    float*       out   = (float*)d_out;

    const int B     = out_size;            // 1024
    const int vocab = in_sizes[4] / 50;    // 100000

    float* ws_logit = (float*)d_ws;                       // 2*B floats = 8192 B
    uint4* wse      = (uint4*)((char*)d_ws + 8192);       // f16 embeddings
    size_t need     = 8192 + (size_t)vocab * 128;

    if (ws_size >= need) {
        knrm_prep_kernel<<<dim3((vocab + 31) / 32), dim3(256), 0, stream>>>(emb, wse, vocab);
        knrm_pass_pre<<<dim3(2 * B), dim3(256), 0, stream>>>(
            q1, d1, q2, d2, wse, mlp_w, ws_logit);
    } else {
        knrm_pass_fb<<<dim3(2 * B), dim3(256), 0, stream>>>(
            q1, d1, q2, d2, emb, mlp_w, ws_logit);
    }
    knrm_final_kernel<<<dim3((B + 255) / 256), dim3(256), 0, stream>>>(ws_logit, out, B);
}